// Round 10
// baseline (177.301 us; speedup 1.0000x reference)
//
#include <hip/hip_runtime.h>
#include <math.h>

// KAN layer forward, MI355X.
// NUM_IN = NUM_OUT = 128, SIZE = 16384, BATCH = 512, K = 3 (cubic), G = 5.
//
// Reference semantics:
//   s = o*128 + i ;  pre_acts[s,b]   = x[b,i]
//   post_splines[s,b] = mask[s] * sum_j coef[s,j] * B3_j(x[b,i]; grid_s)
//   post_acts[s,b]    = scale_b[s]*silu(x[b,i]) + scale_spline[s]*post_splines[s,b]
//   y[b,i] = sum_o post_acts[o*128+i, b]
// Outputs concatenated: y (512*128), pre_acts.T, post_splines.T, post_acts.T
// (each 512*16384, layout [b][s]).
//
// v10 = v8 (121.2 us) re-partitioned for WIDE stores, one clean variable:
//   - thread owns 4 consecutive i x 2 o x 2 b (16 cells, same as v8) ->
//     all three output streams become dwordx4 stores (12 wave-instrs/thread
//     vs 48 dword). v3b's float4 attempt regressed from bundled divergent
//     coef gathers, NOT the stores; here ALL per-row params (coef stride-9,
//     mask/ss/sb) are LDS-staged, so no divergent gathers exist.
//   - block = 2 o x 16 b x 128 i (4096 cells, same); LDS 12.3 KB -> still
//     8 blocks/CU. Uniform-grid check done block-wide at staging time.
//   - tail: v8 atomics (acquitted by v9: ws+reduce was neutral); memset y.
// History: v6 plain>NT stores; v7 basis hoisting won; v8 LDS coef neutral;
// v9 ws-reduce neutral.

#define N_IN   128
#define SIZEK  16384
#define BATCH  512
#define CPAD   9   // padded coef row stride in LDS (gcd(9,32)=1)

__global__ __launch_bounds__(256) void kan_fwd(
    const float* __restrict__ x,            // [512][128]
    const float* __restrict__ scale_b,      // [16384]
    const float* __restrict__ scale_spline, // [16384]
    const float* __restrict__ coef,         // [16384][8]
    const float* __restrict__ mask,         // [16384]
    const float* __restrict__ knots,        // [16384][6]
    float* __restrict__ y,                  // [512][128] (pre-zeroed)
    float* __restrict__ pre_out,            // [512][16384]
    float* __restrict__ spl_out,            // [512][16384]
    float* __restrict__ post_out)           // [512][16384]
{
    __shared__ float shc[256 * CPAD];   // 9216 B  coef, stride-9
    __shared__ float shmk[256];         // mask
    __shared__ float shss[256];         // scale_spline
    __shared__ float shsb[256];         // scale_b
    __shared__ int   shflag;            // block-wide uniform-grid flag

    const int tid = threadIdx.x;
    const int iq  = tid & 31;            // i-quad id (4 consecutive i)
    const int bl  = tid >> 5;            // batch lane (0..7)
    const int ob  = blockIdx.x >> 5;     // o-pair id (64); consecutive blocks share ob
    const int bgp = blockIdx.x & 31;     // batch-group (32 groups of 16)
    const int o0  = ob << 1;
    const int b16 = bgp << 4;
    const int i0  = iq << 2;
    const int s_base = o0 << 7;          // first of the block's 256 s-rows

    // ---- stage coef rows (coalesced float4 reads, padded b32 writes)
    {
        const float4* src = (const float4*)(coef + (size_t)s_base * 8); // 512 vec4
#pragma unroll
        for (int k = 0; k < 2; ++k) {
            const int f4  = k * 256 + tid;        // [0,512)
            const float4 v = src[f4];
            const int row = f4 >> 1;
            const int col = (f4 & 1) << 2;
            float* d = &shc[row * CPAD + col];
            d[0] = v.x; d[1] = v.y; d[2] = v.z; d[3] = v.w;
        }
    }

    // ---- stage per-row scalars (1 row/thread) + uniform-grid row check
    bool rok;
    {
        const int s = s_base + tid;
        shmk[tid] = mask[s];
        shss[tid] = scale_spline[s];
        shsb[tid] = scale_b[s];
        const float k0  = knots[s * 6];
        const float k5  = knots[s * 6 + 5];
        const float k0r = knots[s_base * 6];       // broadcast loads
        const float k5r = knots[s_base * 6 + 5];
        rok = (k0 == k0r) && (k5 == k5r);
    }
    if (tid == 0) shflag = 1;
    __syncthreads();                     // staging + flag init visible
    if (!rok) shflag = 0;
    __syncthreads();                     // flag final; LDS readable
    const bool fast = (shflag != 0);

    // derived grid params (valid when fast; from block row 0, broadcast)
    const float k0r  = knots[s_base * 6];
    const float k5r  = knots[s_base * 6 + 5];
    const float h    = (k5r - k0r) * 0.2f;         // (g_last-g_first)/G, G=5
    const float invh = 1.0f / h;
    const float e0   = k0r - 3.0f * h;

#pragma unroll 1   // keep basis live-range to one batch at a time (VGPR cap)
    for (int t = 0; t < 2; ++t) {
        const int b = b16 + bl + (t << 3);
        const float4 xv = *(const float4*)(x + b * N_IN + i0);
        const float xa[4] = {xv.x, xv.y, xv.z, xv.w};
        float sil[4], ys[4];
#pragma unroll
        for (int ii = 0; ii < 4; ++ii) {
            sil[ii] = xa[ii] / (1.0f + __expf(-xa[ii]));
            ys[ii]  = 0.0f;
        }

        if (fast) {
            // basis per i (reused across the 2 o's)
            int   jc[4][4];
            float wv[4][4];
#pragma unroll
            for (int ii = 0; ii < 4; ++ii) {
                const float u  = (xa[ii] - e0) * invh;
                const float mf = floorf(u);
                const int   m  = (int)mf;
                const float tt = u - mf;
                const bool inr = (m >= 0) && (m <= 10);
                const float t2  = tt * tt;
                const float t3  = t2 * tt;
                const float omt = 1.0f - tt;
                float w[4];
                w[0] = omt * omt * omt * (1.0f / 6.0f);
                w[1] = (3.0f * t3 - 6.0f * t2 + 4.0f) * (1.0f / 6.0f);
                w[2] = (-3.0f * t3 + 3.0f * t2 + 3.0f * tt + 1.0f) * (1.0f / 6.0f);
                w[3] = t3 * (1.0f / 6.0f);
                const int jlo = m - 3;
#pragma unroll
                for (int rr = 0; rr < 4; ++rr) {
                    const int j = jlo + rr;
                    jc[ii][rr] = min(max(j, 0), 7);
                    wv[ii][rr] = (inr && j >= 0 && j <= 7) ? w[rr] : 0.0f;
                }
            }

#pragma unroll
            for (int oo = 0; oo < 2; ++oo) {
                const int rbase = (oo << 7) + i0;   // row within block's 256
                float sp[4], po[4];
#pragma unroll
                for (int ii = 0; ii < 4; ++ii) {
                    const float* __restrict__ cs = &shc[(rbase + ii) * CPAD];
                    float spline = 0.0f;
#pragma unroll
                    for (int rr = 0; rr < 4; ++rr)
                        spline = fmaf(cs[jc[ii][rr]], wv[ii][rr], spline);
                    const float splm = spline * shmk[rbase + ii];
                    sp[ii] = splm;
                    po[ii] = fmaf(shsb[rbase + ii], sil[ii],
                                  shss[rbase + ii] * splm);
                    ys[ii] += po[ii];
                }
                const size_t idx = (size_t)b * SIZEK + (size_t)(s_base + rbase);
                *(float4*)(pre_out  + idx) = xv;
                *(float4*)(spl_out  + idx) = make_float4(sp[0], sp[1], sp[2], sp[3]);
                *(float4*)(post_out + idx) = make_float4(po[0], po[1], po[2], po[3]);
            }
        } else {
            // ---- slow path: per-row grid (general knots), params from LDS
#pragma unroll
            for (int oo = 0; oo < 2; ++oo) {
                const int rbase = (oo << 7) + i0;
                float sp[4], po[4];
#pragma unroll
                for (int ii = 0; ii < 4; ++ii) {
                    const int s = s_base + rbase + ii;
                    const float k0 = knots[s * 6];
                    const float k5 = knots[s * 6 + 5];
                    const float hh = (k5 - k0) * 0.2f;
                    const float ih = 1.0f / hh;
                    const float es = k0 - 3.0f * hh;

                    const float u  = (xa[ii] - es) * ih;
                    const float mf = floorf(u);
                    const int   m  = (int)mf;
                    const float tt = u - mf;
                    const bool inr = (m >= 0) && (m <= 10);
                    const float t2  = tt * tt;
                    const float t3  = t2 * tt;
                    const float omt = 1.0f - tt;
                    float w[4];
                    w[0] = omt * omt * omt * (1.0f / 6.0f);
                    w[1] = (3.0f * t3 - 6.0f * t2 + 4.0f) * (1.0f / 6.0f);
                    w[2] = (-3.0f * t3 + 3.0f * t2 + 3.0f * tt + 1.0f) * (1.0f / 6.0f);
                    w[3] = t3 * (1.0f / 6.0f);

                    const int jlo = m - 3;
                    const float* __restrict__ cs = &shc[(rbase + ii) * CPAD];
                    float spline = 0.0f;
#pragma unroll
                    for (int rr = 0; rr < 4; ++rr) {
                        const int j   = jlo + rr;
                        const int jcr = min(max(j, 0), 7);
                        const float wvv = (inr && j >= 0 && j <= 7) ? w[rr] : 0.0f;
                        spline = fmaf(cs[jcr], wvv, spline);
                    }
                    const float splm = spline * shmk[rbase + ii];
                    sp[ii] = splm;
                    po[ii] = fmaf(shsb[rbase + ii], sil[ii],
                                  shss[rbase + ii] * splm);
                    ys[ii] += po[ii];
                }
                const size_t idx = (size_t)b * SIZEK + (size_t)(s_base + rbase);
                *(float4*)(pre_out  + idx) = xv;
                *(float4*)(spl_out  + idx) = make_float4(sp[0], sp[1], sp[2], sp[3]);
                *(float4*)(post_out + idx) = make_float4(po[0], po[1], po[2], po[3]);
            }
        }

        // y partials for this batch (summed over the block's 2 o's in-thread)
#pragma unroll
        for (int ii = 0; ii < 4; ++ii)
            atomicAdd(&y[b * N_IN + i0 + ii], ys[ii]);
    }
}

extern "C" void kernel_launch(void* const* d_in, const int* in_sizes, int n_in,
                              void* d_out, int out_size, void* d_ws, size_t ws_size,
                              hipStream_t stream) {
    const float* x            = (const float*)d_in[0];
    const float* scale_b      = (const float*)d_in[1];
    const float* scale_spline = (const float*)d_in[2];
    const float* coef         = (const float*)d_in[3];
    const float* mask         = (const float*)d_in[4];
    const float* knots        = (const float*)d_in[5];

    float* out  = (float*)d_out;
    float* y    = out;                         // 512*128      = 65536
    float* pre  = y + 512 * 128;               // 512*16384    = 8388608
    float* spl  = pre + (size_t)512 * 16384;
    float* post = spl + (size_t)512 * 16384;

    // y is accumulated with atomics; harness poisons d_out with 0xAA.
    (void)hipMemsetAsync(y, 0, BATCH * N_IN * sizeof(float), stream);

    // blocks: 64 o-pairs x 32 batch-groups = 2048; 256 threads each.
    dim3 grid(2048), block(256);
    kan_fwd<<<grid, block, 0, stream>>>(x, scale_b, scale_spline, coef, mask,
                                        knots, y, pre, spl, post);
}

// Round 11
// 120.114 us; speedup vs baseline: 1.4761x; 1.4761x over previous
//
#include <hip/hip_runtime.h>
#include <math.h>

// KAN layer forward, MI355X.
// NUM_IN = NUM_OUT = 128, SIZE = 16384, BATCH = 512, K = 3 (cubic), G = 5.
//
// Reference semantics:
//   s = o*128 + i ;  pre_acts[s,b]   = x[b,i]
//   post_splines[s,b] = mask[s] * sum_j coef[s,j] * B3_j(x[b,i]; grid_s)
//   post_acts[s,b]    = scale_b[s]*silu(x[b,i]) + scale_spline[s]*post_splines[s,b]
//   y[b,i] = sum_o post_acts[o*128+i, b]
// Outputs concatenated: y (512*128), pre_acts.T, post_splines.T, post_acts.T
// (each 512*16384, layout [b][s]).
//
// v11 = v8 VERBATIM (121.2 us best-known). Session ladder:
//   v1  161 us  baseline (2 blocks/CU, latency-bound)
//   v2  129 us  8 blocks/CU occupancy + prefetched params     [WIN]
//   v3b 160 us  float4 stores + divergent coef gathers        [REGRESS: TA choke]
//   v4  127 us  cndmask-tree coef select                      [WIN]
//   v5  145 us  block-o-ownership, no atomics                 [REGRESS]
//   v6  126 us  plain stores (NT ablated)                     [WIN]
//   v7  122 us  wave-uniform-grid basis hoisting              [WIN]
//   v8  121 us  LDS coef stride-9 select                      [neutral, kept]
//   v9  123 us  ws+reduce tail (atomics acquitted)            [neutral]
//   v10 177 us  4-i repartition for dwordx4 stores            [REGRESS:
//        8-way LDS conflict inherent (lane row-stride 4 => gcd(4*CPAD,32)>=4),
//        atomic targets 2x => +64 MB y-line ping-pong write amplification]
// Conclusion: v8's mapping (thread = 1 i x 4 o x 4 b, lane-consecutive i)
// is the correct architecture; every repartition pays more than it saves.
// Residual: kan_fwd ~29 us vs 16.5 us write floor (100.6 MB @ 6.2 TB/s) —
// store-granularity + tail structure, no remaining proven lever.

#define N_IN   128
#define SIZEK  16384
#define BATCH  512

#define TB 4    // batches per thread
#define CO 4    // o-values per thread
#define CPAD 9  // padded coef row stride in LDS (gcd(9,32)=1 -> conflict-free
                // because lane->row stride is 1 in THIS mapping)

__global__ __launch_bounds__(256) void kan_fwd(
    const float* __restrict__ x,            // [512][128]
    const float* __restrict__ scale_b,      // [16384]
    const float* __restrict__ scale_spline, // [16384]
    const float* __restrict__ coef,         // [16384][8]
    const float* __restrict__ mask,         // [16384]
    const float* __restrict__ knots,        // [16384][6]
    float* __restrict__ y,                  // [512][128] (pre-zeroed)
    float* __restrict__ pre_out,            // [512][16384]
    float* __restrict__ spl_out,            // [512][16384]
    float* __restrict__ post_out)           // [512][16384]
{
    __shared__ float shc[512 * CPAD];       // 18432 B -> still 8 blocks/CU

    const int tid = threadIdx.x;
    const int g  = blockIdx.x * 256 + tid;
    const int i  = g & 127;          // input index (lane-consecutive -> coalesced)
    const int r  = g >> 7;           // [0, 4096)
    const int oc = r >> 7;           // o-chunk id, BLOCK-UNIFORM (32 chunks of 4 o)
    const int bg = r & 127;          // batch-group id (128 groups of 4)
    const int o0 = oc << 2;
    const int b0 = bg << 2;
    const int s_base = o0 << 7;      // first of the block's 512 consecutive s-rows

    // ---- stage the block's coef rows into LDS (coalesced float4 reads,
    //      padded-stride b32 writes). One-time cost per block.
    {
        const float4* src = (const float4*)(coef + (size_t)s_base * 8); // 1024 vec4
#pragma unroll
        for (int k = 0; k < 4; ++k) {
            const int f4  = k * 256 + tid;        // [0,1024)
            const float4 v = src[f4];
            const int row = f4 >> 1;              // [0,512)
            const int col = (f4 & 1) << 2;        // 0 or 4
            float* d = &shc[row * CPAD + col];
            d[0] = v.x; d[1] = v.y; d[2] = v.z; d[3] = v.w;
        }
    }

    float xv[TB], sil[TB], ysum[TB];
#pragma unroll
    for (int t = 0; t < TB; ++t) {
        const float xx = x[(b0 + t) * N_IN + i];
        xv[t]   = xx;
        sil[t]  = xx / (1.0f + __expf(-xx));   // silu(x) = x * sigmoid(x)
        ysum[t] = 0.0f;
    }

    // ---- prefetch per-edge scalars for the CO rows (independent loads)
    float e0v[CO], ihv[CO], mkv[CO], sbv[CO], ssv[CO];
#pragma unroll
    for (int oo = 0; oo < CO; ++oo) {
        const int s = ((o0 + oo) << 7) | i;
        const float k0 = knots[s * 6];
        const float k5 = knots[s * 6 + 5];
        const float h  = (k5 - k0) * 0.2f;     // (g_last-g_first)/G, G=5
        ihv[oo] = 1.0f / h;
        e0v[oo] = k0 - 3.0f * h;               // leftmost extended knot
        mkv[oo] = mask[s];
        sbv[oo] = scale_b[s];
        ssv[oo] = scale_spline[s];
    }

    __syncthreads();                 // coef staging complete (uniform barrier)

    // wave-uniform check: do all 4 rows share the same (e0, invh)?
    const bool same_lane =
        (e0v[1] == e0v[0]) && (ihv[1] == ihv[0]) &&
        (e0v[2] == e0v[0]) && (ihv[2] == ihv[0]) &&
        (e0v[3] == e0v[0]) && (ihv[3] == ihv[0]);

    if (__all(same_lane)) {
        // ======== FAST PATH: basis hoisted across the CO o-chunks ========
        const float e0   = e0v[0];
        const float invh = ihv[0];
#pragma unroll
        for (int t = 0; t < TB; ++t) {
            const float u  = (xv[t] - e0) * invh;
            const float mf = floorf(u);
            const int   m  = (int)mf;
            const float tt = u - mf;
            const bool inr = (m >= 0) && (m <= 10);

            const float t2  = tt * tt;
            const float t3  = t2 * tt;
            const float omt = 1.0f - tt;
            float w[4];
            w[0] = omt * omt * omt * (1.0f / 6.0f);
            w[1] = (3.0f * t3 - 6.0f * t2 + 4.0f) * (1.0f / 6.0f);
            w[2] = (-3.0f * t3 + 3.0f * t2 + 3.0f * tt + 1.0f) * (1.0f / 6.0f);
            w[3] = t3 * (1.0f / 6.0f);

            // masked weights + clamped select indices, once per t
            const int jlo = m - 3;
            int   jc[4];
            float wv[4];
#pragma unroll
            for (int rr = 0; rr < 4; ++rr) {
                const int j = jlo + rr;
                jc[rr] = min(max(j, 0), 7);
                wv[rr] = (inr && j >= 0 && j <= 7) ? w[rr] : 0.0f;
            }

#pragma unroll
            for (int oo = 0; oo < CO; ++oo) {
                const int s = ((o0 + oo) << 7) | i;
                const float* __restrict__ cs = &shc[(oo * 128 + i) * CPAD];

                float spline = 0.0f;
#pragma unroll
                for (int rr = 0; rr < 4; ++rr)
                    spline = fmaf(cs[jc[rr]], wv[rr], spline);  // ds_read_b32

                const float splm = spline * mkv[oo];
                const float post = fmaf(sbv[oo], sil[t], ssv[oo] * splm);

                const size_t idx = (size_t)(b0 + t) * SIZEK + (size_t)s;
                pre_out[idx]  = xv[t];
                spl_out[idx]  = splm;
                post_out[idx] = post;
                ysum[t] += post;
            }
        }
    } else {
        // ======== SLOW PATH: per-oo basis (general knots), LDS coef ========
#pragma unroll
        for (int oo = 0; oo < CO; ++oo) {
            const int s = ((o0 + oo) << 7) | i;
            const float e0   = e0v[oo];
            const float invh = ihv[oo];
            const float mk   = mkv[oo];
            const float sb   = sbv[oo];
            const float ss   = ssv[oo];
            const float* __restrict__ cs = &shc[(oo * 128 + i) * CPAD];

#pragma unroll
            for (int t = 0; t < TB; ++t) {
                const float u  = (xv[t] - e0) * invh;
                const float mf = floorf(u);
                const int   m  = (int)mf;
                const float tt = u - mf;
                const bool inr = (m >= 0) && (m <= 10);

                const float t2  = tt * tt;
                const float t3  = t2 * tt;
                const float omt = 1.0f - tt;
                float w[4];
                w[0] = omt * omt * omt * (1.0f / 6.0f);
                w[1] = (3.0f * t3 - 6.0f * t2 + 4.0f) * (1.0f / 6.0f);
                w[2] = (-3.0f * t3 + 3.0f * t2 + 3.0f * tt + 1.0f) * (1.0f / 6.0f);
                w[3] = t3 * (1.0f / 6.0f);

                const int jlo = m - 3;
                float spline = 0.0f;
#pragma unroll
                for (int rr = 0; rr < 4; ++rr) {
                    const int j   = jlo + rr;
                    const int jcr = min(max(j, 0), 7);
                    const float wvv = (inr && j >= 0 && j <= 7) ? w[rr] : 0.0f;
                    spline = fmaf(cs[jcr], wvv, spline);
                }

                const float splm = spline * mk;
                const float post = fmaf(sb, sil[t], ss * splm);

                const size_t idx = (size_t)(b0 + t) * SIZEK + (size_t)s;
                pre_out[idx]  = xv[t];
                spl_out[idx]  = splm;
                post_out[idx] = post;
                ysum[t] += post;
            }
        }
    }

#pragma unroll
    for (int t = 0; t < TB; ++t)
        atomicAdd(&y[(b0 + t) * N_IN + i], ysum[t]);
}

extern "C" void kernel_launch(void* const* d_in, const int* in_sizes, int n_in,
                              void* d_out, int out_size, void* d_ws, size_t ws_size,
                              hipStream_t stream) {
    const float* x            = (const float*)d_in[0];
    const float* scale_b      = (const float*)d_in[1];
    const float* scale_spline = (const float*)d_in[2];
    const float* coef         = (const float*)d_in[3];
    const float* mask         = (const float*)d_in[4];
    const float* knots        = (const float*)d_in[5];

    float* out  = (float*)d_out;
    float* y    = out;                         // 512*128      = 65536
    float* pre  = y + 512 * 128;               // 512*16384    = 8388608
    float* spl  = pre + (size_t)512 * 16384;
    float* post = spl + (size_t)512 * 16384;

    // y is accumulated with atomics; harness poisons d_out with 0xAA.
    (void)hipMemsetAsync(y, 0, BATCH * N_IN * sizeof(float), stream);

    // threads = 128 i * 32 o-chunks * 128 b-groups = 524288 -> 2048 blocks
    dim3 grid(2048), block(256);
    kan_fwd<<<grid, block, 0, stream>>>(x, scale_b, scale_spline, coef, mask,
                                        knots, y, pre, spl, post);
}